// Round 1
// baseline (1240.890 us; speedup 1.0000x reference)
//
#include <hip/hip_runtime.h>

typedef unsigned int uint;
typedef unsigned short ushort;
typedef __attribute__((ext_vector_type(8))) __bf16 bf16x8;
typedef __attribute__((ext_vector_type(8))) ushort u16x8;
typedef __attribute__((ext_vector_type(4))) float f32x4;
typedef __attribute__((ext_vector_type(4))) float fvec4;

#define DEV static __device__ __forceinline__

DEV ushort f2b(float f){ uint u = __float_as_uint(f); return (ushort)((u + 0x7fffu + ((u >> 16) & 1u)) >> 16); }
DEV float b2f(ushort h){ return __uint_as_float(((uint)h) << 16); }

// ---------------------------------------------------------------------------
// Weight conversion fp32 -> bf16 (+ bias concat for off/A projection)
// ---------------------------------------------------------------------------
__global__ void k_convert(const float* wqkv, const float* wo, const float* woff, const float* wA,
                          const float* wv, const float* wm, const float* w1, const float* w2,
                          const float* boff, const float* bA,
                          ushort* d_wqkv, ushort* d_wo, ushort* d_woffA, ushort* d_wv,
                          ushort* d_wm, ushort* d_w1, ushort* d_w2, float* d_boffA)
{
    int i = blockIdx.x * 256 + threadIdx.x;
    if (i < 196608) { d_wqkv[i] = f2b(wqkv[i]); return; } i -= 196608;
    if (i < 65536)  { d_wo[i] = f2b(wo[i]); return; }     i -= 65536;
    if (i < 65536)  { d_woffA[i] = f2b(woff[i]); return; } i -= 65536;
    if (i < 32768)  { d_woffA[65536 + i] = f2b(wA[i]); return; } i -= 32768;
    if (i < 65536)  { d_wv[i] = f2b(wv[i]); return; }     i -= 65536;
    if (i < 65536)  { d_wm[i] = f2b(wm[i]); return; }     i -= 65536;
    if (i < 524288) { d_w1[i] = f2b(w1[i]); return; }     i -= 524288;
    if (i < 524288) { d_w2[i] = f2b(w2[i]); return; }     i -= 524288;
    if (i < 256)    { d_boffA[i] = boff[i]; return; }     i -= 256;
    if (i < 128)    { d_boffA[256 + i] = bA[i]; return; }
}

// qk = tgt + query_pos (bf16), tgt (bf16)
__global__ void k_prep(const float* __restrict__ tgt, const float* __restrict__ qpos,
                       ushort* __restrict__ qk_b, ushort* __restrict__ tgt_b)
{
    int i = blockIdx.x * 256 + threadIdx.x;   // < 1228800 exact
    float t = tgt[i];
    qk_b[i] = f2b(t + qpos[i]);
    tgt_b[i] = f2b(t);
}

// ---------------------------------------------------------------------------
// Generic bf16 GEMM: D[m,n] = sum_k A[m,k]*B[n,k] + bias[n]  (A:[M,K], B:[N,K])
// BM=BN=128, BK=32, 4 waves (2x2), each wave 64x64 via 4x4 16x16x32 mfma.
// LDS layout [g=k/8][row][8] -> conflict-free b128 fragment reads.
// ---------------------------------------------------------------------------
__global__ __launch_bounds__(256) void k_gemm(
    const ushort* __restrict__ A, const ushort* __restrict__ B,
    const float* __restrict__ bias,
    float* __restrict__ outf, ushort* __restrict__ outb,
    int M, int N, int K, int relu)
{
    __shared__ ushort ldsA[4096];
    __shared__ ushort ldsB[4096];
    int tid = threadIdx.x;
    int lane = tid & 63, wave = tid >> 6;
    int wm = wave >> 1, wn = wave & 1;
    int mt = blockIdx.x, nt = blockIdx.y;

    f32x4 acc[4][4];
    #pragma unroll
    for (int i = 0; i < 4; i++)
        #pragma unroll
        for (int j = 0; j < 4; j++) acc[i][j] = (f32x4)(0.0f);

    int ksteps = K >> 5;
    for (int ks = 0; ks < ksteps; ks++) {
        #pragma unroll
        for (int p = 0; p < 2; p++) {
            int sidx = p * 2048 + tid * 8;
            int g = sidx >> 10;
            int mm = (sidx & 1023) >> 3;
            int row = mt * 128 + mm; if (row >= M) row = M - 1;
            *(u16x8*)&ldsA[sidx] = *(const u16x8*)(A + (size_t)row * K + ks * 32 + g * 8);
            int nn = nt * 128 + mm;
            *(u16x8*)&ldsB[sidx] = *(const u16x8*)(B + (size_t)nn * K + ks * 32 + g * 8);
        }
        __syncthreads();
        int g = lane >> 4, fr = lane & 15;
        bf16x8 av[4], bv[4];
        #pragma unroll
        for (int i = 0; i < 4; i++) av[i] = *(const bf16x8*)&ldsA[g * 1024 + (wm * 64 + i * 16 + fr) * 8];
        #pragma unroll
        for (int j = 0; j < 4; j++) bv[j] = *(const bf16x8*)&ldsB[g * 1024 + (wn * 64 + j * 16 + fr) * 8];
        #pragma unroll
        for (int i = 0; i < 4; i++)
            #pragma unroll
            for (int j = 0; j < 4; j++)
                acc[i][j] = __builtin_amdgcn_mfma_f32_16x16x32_bf16(av[i], bv[j], acc[i][j], 0, 0, 0);
        __syncthreads();
    }

    int g = lane >> 4, fr = lane & 15;
    #pragma unroll
    for (int i = 0; i < 4; i++) {
        #pragma unroll
        for (int j = 0; j < 4; j++) {
            int col = nt * 128 + wn * 64 + j * 16 + fr;
            float bb = bias ? bias[col] : 0.0f;
            #pragma unroll
            for (int r2 = 0; r2 < 4; r2++) {
                int row = mt * 128 + wm * 64 + i * 16 + g * 4 + r2;
                if (row < M) {
                    float v = acc[i][j][r2] + bb;
                    if (relu) v = fmaxf(v, 0.0f);
                    if (outf) outf[(size_t)row * N + col] = v;
                    else      outb[(size_t)row * N + col] = f2b(v);
                }
            }
        }
    }
}

// ---------------------------------------------------------------------------
// Value projection GEMM, fused (mem+pos) add + bf16 convert on A-staging.
// A panel [128][256] bf16 (64KB LDS, XOR-swizzled rows), full K resident;
// B (W_v bf16, 128KB, L2-resident) read direct from global. N=256 in 2 tiles.
// ---------------------------------------------------------------------------
__global__ __launch_bounds__(256) void k_gemm_vals(
    const float* __restrict__ mem, const float* __restrict__ pos,
    const ushort* __restrict__ Wv, const float* __restrict__ bias,
    ushort* __restrict__ out)
{
    __shared__ ushort ldsA[32768];   // 64 KB
    int tid = threadIdx.x;
    int lane = tid & 63, wave = tid >> 6;
    int wm = wave >> 1, wn = wave & 1;
    int mt = blockIdx.x;

    #pragma unroll
    for (int it = 0; it < 16; it++) {
        int e0 = it * 2048 + tid * 8;
        int mm = e0 >> 8;
        int k0 = e0 & 255;
        size_t gb = (size_t)(mt * 128 + mm) * 256 + k0;
        const fvec4* pm = (const fvec4*)(mem + gb);
        const fvec4* pp = (const fvec4*)(pos + gb);
        fvec4 a0 = pm[0], a1 = pm[1];
        fvec4 c0 = pp[0], c1 = pp[1];
        u16x8 v;
        v[0] = f2b(a0[0] + c0[0]); v[1] = f2b(a0[1] + c0[1]);
        v[2] = f2b(a0[2] + c0[2]); v[3] = f2b(a0[3] + c0[3]);
        v[4] = f2b(a1[0] + c1[0]); v[5] = f2b(a1[1] + c1[1]);
        v[6] = f2b(a1[2] + c1[2]); v[7] = f2b(a1[3] + c1[3]);
        int byteoff = (mm * 512 + k0 * 2) ^ ((mm & 7) << 4);
        *(u16x8*)((char*)ldsA + byteoff) = v;
    }
    __syncthreads();

    int g = lane >> 4, fr = lane & 15;
    #pragma unroll 1
    for (int nt = 0; nt < 2; nt++) {
        f32x4 acc[4][4];
        #pragma unroll
        for (int i = 0; i < 4; i++)
            #pragma unroll
            for (int j = 0; j < 4; j++) acc[i][j] = (f32x4)(0.0f);
        #pragma unroll 1
        for (int ks = 0; ks < 8; ks++) {
            bf16x8 av[4], bv[4];
            #pragma unroll
            for (int i = 0; i < 4; i++) {
                int mrow = wm * 64 + i * 16 + fr;
                int byteoff = (mrow * 512 + ks * 64 + g * 16) ^ ((mrow & 7) << 4);
                av[i] = *(const bf16x8*)((const char*)ldsA + byteoff);
            }
            #pragma unroll
            for (int j = 0; j < 4; j++) {
                int nrow = nt * 128 + wn * 64 + j * 16 + fr;
                bv[j] = *(const bf16x8*)(Wv + (size_t)nrow * 256 + ks * 32 + g * 8);
            }
            #pragma unroll
            for (int i = 0; i < 4; i++)
                #pragma unroll
                for (int j = 0; j < 4; j++)
                    acc[i][j] = __builtin_amdgcn_mfma_f32_16x16x32_bf16(av[i], bv[j], acc[i][j], 0, 0, 0);
        }
        #pragma unroll
        for (int i = 0; i < 4; i++) {
            #pragma unroll
            for (int j = 0; j < 4; j++) {
                int col = nt * 128 + wn * 64 + j * 16 + fr;
                float bb = bias[col];
                #pragma unroll
                for (int r2 = 0; r2 < 4; r2++) {
                    int row = mt * 128 + wm * 64 + i * 16 + g * 4 + r2;
                    out[(size_t)row * 256 + col] = f2b(acc[i][j][r2] + bb);
                }
            }
        }
    }
}

// ---------------------------------------------------------------------------
// Self-attention: block per (qtile=32, head, batch). K fp32 / V bf16 in LDS
// (stride 33 -> conflict-free). 8 threads per q-row split the m-range.
// ---------------------------------------------------------------------------
__global__ __launch_bounds__(256) void k_attn(
    const float* __restrict__ qkbuf, const float* __restrict__ vbuf,
    ushort* __restrict__ ctx)
{
    __shared__ float  Ks[9900];   // [300][33] padded
    __shared__ ushort Vs[9900];
    int qt = blockIdx.x, h = blockIdx.y, b = blockIdx.z;
    int tid = threadIdx.x;
    for (int i = tid; i < 9600; i += 256) {
        int m = i >> 5, d = i & 31;
        Ks[m * 33 + d] = qkbuf[(size_t)(m * 16 + b) * 512 + 256 + h * 32 + d];
        Vs[m * 33 + d] = f2b(vbuf[(size_t)(m * 16 + b) * 256 + h * 32 + d]);
    }
    __syncthreads();

    int r = tid >> 3, c = tid & 7;
    int qrow = qt * 32 + r;
    bool qv = qrow < 300;
    int qa = qv ? qrow : 0;

    float qreg[32];
    {
        size_t qb = (size_t)(qa * 16 + b) * 512 + h * 32;
        #pragma unroll
        for (int d = 0; d < 32; d++) qreg[d] = qkbuf[qb + d];
    }
    const float scale = 0.17677669529663687f;

    float s[38];
    float mx = -1e30f;
    #pragma unroll
    for (int j = 0; j < 38; j++) {
        int m = c + (j << 3);
        if (m < 300) {
            float dot = 0.0f;
            #pragma unroll
            for (int d = 0; d < 32; d++) dot += qreg[d] * Ks[m * 33 + d];
            s[j] = dot * scale;
            mx = fmaxf(mx, s[j]);
        } else s[j] = -1e30f;
    }
    #pragma unroll
    for (int o = 1; o < 8; o <<= 1) mx = fmaxf(mx, __shfl_xor(mx, o));
    float sum = 0.0f;
    #pragma unroll
    for (int j = 0; j < 38; j++) { s[j] = __expf(s[j] - mx); sum += s[j]; }
    #pragma unroll
    for (int o = 1; o < 8; o <<= 1) sum += __shfl_xor(sum, o);
    float inv = 1.0f / sum;

    float acc[32];
    #pragma unroll
    for (int d = 0; d < 32; d++) acc[d] = 0.0f;
    #pragma unroll
    for (int j = 0; j < 38; j++) {
        int m = c + (j << 3);
        if (m < 300) {
            float p = s[j];
            #pragma unroll
            for (int d = 0; d < 32; d++) acc[d] += p * b2f(Vs[m * 33 + d]);
        }
    }
    #pragma unroll
    for (int d = 0; d < 32; d++) {
        #pragma unroll
        for (int o = 1; o < 8; o <<= 1) acc[d] += __shfl_xor(acc[d], o);
    }
    if (c == 0 && qv) {
        size_t ob = (size_t)(qrow * 16 + b) * 256 + h * 32;
        #pragma unroll
        for (int d = 0; d < 32; d++) ctx[ob + d] = f2b(acc[d] * inv);
    }
}

// ---------------------------------------------------------------------------
// MS-deform sampling: block per (b,q); thread = head*32 + dim.
// ---------------------------------------------------------------------------
__global__ __launch_bounds__(256) void k_deform(
    const float* __restrict__ offA, const float* __restrict__ refp,
    const ushort* __restrict__ vals, ushort* __restrict__ out)
{
    int bid = blockIdx.x;            // b*300 + q
    int b = bid / 300, q = bid - b * 300;
    int t = threadIdx.x;
    int h = t >> 5, d = t & 31;

    __shared__ float offs[384];
    for (int i = t; i < 384; i += 256) offs[i] = offA[(size_t)bid * 384 + i];
    __syncthreads();

    float rx = refp[(q * 16 + b) * 2 + 0];
    float ry = refp[(q * 16 + b) * 2 + 1];

    float e[16]; float mx = -1e30f;
    #pragma unroll
    for (int j = 0; j < 16; j++) { e[j] = offs[256 + h * 16 + j]; mx = fmaxf(mx, e[j]); }
    float ssum = 0.0f;
    #pragma unroll
    for (int j = 0; j < 16; j++) { e[j] = __expf(e[j] - mx); ssum += e[j]; }
    float inv = 1.0f / ssum;

    const int HS[4]  = {16, 32, 64, 128};
    const int LOF[4] = {0, 1048576, 5242880, 22020096};
    float acc = 0.0f;
    #pragma unroll
    for (int l = 0; l < 4; l++) {
        int W = HS[l];
        size_t base = (size_t)LOF[l] + (size_t)b * W * W * 256;
        float sc = (float)(W - 1);
        #pragma unroll
        for (int k = 0; k < 4; k++) {
            float ox = offs[((h * 4 + l) * 4 + k) * 2 + 0];
            float oy = offs[((h * 4 + l) * 4 + k) * 2 + 1];
            float px = rx * sc + ox;
            float py = ry * sc + oy;
            float x0f = floorf(px), y0f = floorf(py);
            int x0 = (int)x0f, y0 = (int)y0f;
            float wx = px - x0f, wy = py - y0f;
            float sval = 0.0f;
            #define CORNER(XI, YI, WW) { \
                int xi = (XI), yi = (YI); \
                bool ok = (xi >= 0) && (xi < W) && (yi >= 0) && (yi < W); \
                int xc = min(max(xi, 0), W - 1), yc = min(max(yi, 0), W - 1); \
                float vv = b2f(vals[base + (size_t)(yc * W + xc) * 256 + (h << 5) + d]); \
                sval += vv * (ok ? (WW) : 0.0f); }
            CORNER(x0,     y0,     (1.0f - wx) * (1.0f - wy));
            CORNER(x0 + 1, y0,     wx * (1.0f - wy));
            CORNER(x0,     y0 + 1, (1.0f - wx) * wy);
            CORNER(x0 + 1, y0 + 1, wx * wy);
            #undef CORNER
            acc += e[l * 4 + k] * sval;
        }
    }
    out[(size_t)bid * 256 + t] = f2b(acc * inv);
}

// ---------------------------------------------------------------------------
// LayerNorm(resid + branch), optional row permutation, fp32 + optional bf16 out
// mode 0: same rows; mode 1: (l*16+b) -> (b*300+l); mode 2: (b*300+l) -> (l*16+b)
// ---------------------------------------------------------------------------
__global__ __launch_bounds__(256) void k_ln(
    const float* __restrict__ resid, const float* __restrict__ branch,
    const float* __restrict__ gam, const float* __restrict__ bet,
    float* __restrict__ outf, ushort* __restrict__ outb, int mode)
{
    int row = blockIdx.x;
    int c = threadIdx.x;
    size_t ib = (size_t)row * 256 + c;
    float x = resid[ib] + branch[ib];
    float s1 = x, s2 = x * x;
    #pragma unroll
    for (int o = 32; o; o >>= 1) { s1 += __shfl_xor(s1, o); s2 += __shfl_xor(s2, o); }
    __shared__ float red[8];
    int lane = c & 63, w = c >> 6;
    if (lane == 0) { red[w] = s1; red[4 + w] = s2; }
    __syncthreads();
    if (c == 0) {
        float a = red[0] + red[1] + red[2] + red[3];
        float b2 = red[4] + red[5] + red[6] + red[7];
        float mu = a * (1.0f / 256.0f);
        float var = b2 * (1.0f / 256.0f) - mu * mu;
        red[0] = mu; red[1] = rsqrtf(var + 1e-5f);
    }
    __syncthreads();
    float mu = red[0], rs = red[1];
    float y = (x - mu) * rs * gam[c] + bet[c];
    int orow;
    if (mode == 0) orow = row;
    else if (mode == 1) { int l = row >> 4, b = row & 15; orow = b * 300 + l; }
    else { int b = row / 300, l = row - b * 300; orow = l * 16 + b; }
    if (outf) outf[(size_t)orow * 256 + c] = y;
    if (outb) outb[(size_t)orow * 256 + c] = f2b(y);
}

// ---------------------------------------------------------------------------
extern "C" void kernel_launch(void* const* d_in, const int* in_sizes, int n_in,
                              void* d_out, int out_size, void* d_ws, size_t ws_size,
                              hipStream_t stream)
{
    (void)in_sizes; (void)n_in; (void)out_size; (void)ws_size;
    const float* tgt  = (const float*)d_in[0];
    const float* qpos = (const float*)d_in[1];
    const float* refp = (const float*)d_in[2];
    const float* mem0 = (const float*)d_in[3];
    const float* pos0 = (const float*)d_in[4];
    const float* mem1 = (const float*)d_in[5];
    const float* pos1 = (const float*)d_in[6];
    const float* mem2 = (const float*)d_in[7];
    const float* pos2 = (const float*)d_in[8];
    const float* mem3 = (const float*)d_in[9];
    const float* pos3 = (const float*)d_in[10];
    const float* Wqkv = (const float*)d_in[11];
    const float* bqkv = (const float*)d_in[12];
    const float* Wo   = (const float*)d_in[13];
    const float* bo   = (const float*)d_in[14];
    const float* Woff = (const float*)d_in[15];
    const float* boff = (const float*)d_in[16];
    const float* WA   = (const float*)d_in[17];
    const float* bA   = (const float*)d_in[18];
    const float* Wv   = (const float*)d_in[19];
    const float* bv   = (const float*)d_in[20];
    const float* Wm   = (const float*)d_in[21];
    const float* bm   = (const float*)d_in[22];
    const float* W1   = (const float*)d_in[23];
    const float* b1   = (const float*)d_in[24];
    const float* W2   = (const float*)d_in[25];
    const float* b2   = (const float*)d_in[26];
    const float* ln1g = (const float*)d_in[27];
    const float* ln1b = (const float*)d_in[28];
    const float* ln2g = (const float*)d_in[29];
    const float* ln2b = (const float*)d_in[30];
    const float* ln3g = (const float*)d_in[31];
    const float* ln3b = (const float*)d_in[32];

    char* ws = (char*)d_ws;
    size_t off = 0;
    auto alloc = [&](size_t bytes) -> char* {
        char* p = ws + off; off += (bytes + 255) & ~(size_t)255; return p;
    };
    ushort* wqkv_b  = (ushort*)alloc(196608 * 2);
    ushort* wo_b    = (ushort*)alloc(65536 * 2);
    ushort* woffA_b = (ushort*)alloc(98304 * 2);
    ushort* wv_b    = (ushort*)alloc(65536 * 2);
    ushort* wm_b    = (ushort*)alloc(65536 * 2);
    ushort* w1_b    = (ushort*)alloc(524288 * 2);
    ushort* w2_b    = (ushort*)alloc(524288 * 2);
    float*  boffA   = (float*) alloc(384 * 4);
    ushort* qk_b    = (ushort*)alloc(1228800 * 2);
    ushort* tgt_b   = (ushort*)alloc(1228800 * 2);
    float*  qkbuf   = (float*) alloc(2457600 * 4);   // [4800,512] Q|K
    float*  vbuf    = (float*) alloc(1228800 * 4);
    ushort* ctx_b   = (ushort*)alloc(1228800 * 2);
    float*  mhaf    = (float*) alloc(1228800 * 4);
    float*  tqf     = (float*) alloc(1228800 * 4);
    ushort* tq_b    = (ushort*)alloc(1228800 * 2);
    float*  offAf   = (float*) alloc(1843200 * 4);   // [4800,384]
    ushort* vals    = (ushort*)alloc(89128960ull * 2);
    ushort* dfo_b   = (ushort*)alloc(1228800 * 2);
    float*  t2f     = (float*) alloc(1228800 * 4);
    float*  tq2f    = (float*) alloc(1228800 * 4);
    ushort* tq2_b   = (ushort*)alloc(1228800 * 2);
    ushort* h_b     = (ushort*)alloc(9830400ull * 2);
    float*  yf      = (float*) alloc(1228800 * 4);

    k_convert<<<6018, 256, 0, stream>>>(Wqkv, Wo, Woff, WA, Wv, Wm, W1, W2, boff, bA,
                                        wqkv_b, wo_b, woffA_b, wv_b, wm_b, w1_b, w2_b, boffA);
    k_prep<<<4800, 256, 0, stream>>>(tgt, qpos, qk_b, tgt_b);

    // QK projection: [4800,512] = qk @ [Wq;Wk].T + bias
    k_gemm<<<dim3(38, 4), 256, 0, stream>>>(qk_b, wqkv_b, bqkv, qkbuf, nullptr, 4800, 512, 256, 0);
    // V projection: [4800,256] = tgt @ Wv_attn.T + bias
    k_gemm<<<dim3(38, 2), 256, 0, stream>>>(tgt_b, wqkv_b + 512 * 256, bqkv + 512, vbuf, nullptr, 4800, 256, 256, 0);
    // attention
    k_attn<<<dim3(10, 8, 16), 256, 0, stream>>>(qkbuf, vbuf, ctx_b);
    // output proj
    k_gemm<<<dim3(38, 2), 256, 0, stream>>>(ctx_b, wo_b, bo, mhaf, nullptr, 4800, 256, 256, 0);
    // LN1, transpose (l,b)->(b,l)
    k_ln<<<4800, 256, 0, stream>>>(tgt, mhaf, ln1g, ln1b, tqf, tq_b, 1);
    // offsets + A logits: [4800,384]
    k_gemm<<<dim3(38, 3), 256, 0, stream>>>(tq_b, woffA_b, boffA, offAf, nullptr, 4800, 384, 256, 0);
    // value projection per level (fused mem+pos add)
    k_gemm_vals<<<32,   256, 0, stream>>>(mem0, pos0, wv_b, bv, vals + 0);
    k_gemm_vals<<<128,  256, 0, stream>>>(mem1, pos1, wv_b, bv, vals + 1048576);
    k_gemm_vals<<<512,  256, 0, stream>>>(mem2, pos2, wv_b, bv, vals + 5242880);
    k_gemm_vals<<<2048, 256, 0, stream>>>(mem3, pos3, wv_b, bv, vals + 22020096);
    // sampling
    k_deform<<<4800, 256, 0, stream>>>(offAf, refp, vals, dfo_b);
    // output proj W_m
    k_gemm<<<dim3(38, 2), 256, 0, stream>>>(dfo_b, wm_b, bm, t2f, nullptr, 4800, 256, 256, 0);
    // LN2
    k_ln<<<4800, 256, 0, stream>>>(tqf, t2f, ln2g, ln2b, tq2f, tq2_b, 0);
    // FFN
    k_gemm<<<dim3(38, 16), 256, 0, stream>>>(tq2_b, w1_b, b1, nullptr, h_b, 4800, 2048, 256, 1);
    k_gemm<<<dim3(38, 2), 256, 0, stream>>>(h_b, w2_b, b2, yf, nullptr, 4800, 256, 2048, 0);
    // LN3 -> d_out with transpose (b,l)->(l,b)
    k_ln<<<4800, 256, 0, stream>>>(tq2f, yf, ln3g, ln3b, (float*)d_out, nullptr, 2);
}